// Round 2
// baseline (317.170 us; speedup 1.0000x reference)
//
#include <hip/hip_runtime.h>

// Unfold: x[B=32, C=64, H=64, W=64] fp32, KH=KW=3, stride=1
// out[b][c*9 + i*3 + j][ho*62 + wo] = x[b][c][ho+i][wo+j]; out [32, 576, 3844].
//
// One block per (b,c) channel. Stage the 16 KB channel in LDS (read from HBM
// exactly once), then emit all 9 k-planes. Loop nest is position-outer /
// k-inner: the ho/wo decode + row-wrap + the 4 LDS source addresses are
// computed ONCE per output float4 position and reused for all 9 k-planes
// (per-k offset is the compile-time constant i*W+j). This cuts VALU per
// 16B store ~3x vs k-outer and puts 36 independent ds_read_b32 in flight
// per position. LDS uses a +1-pad-per-32-floats swizzle (idx -> idx +
// (idx>>5)) so the stride-4-float read pattern is the free 2-way case.
// Stores use __builtin_nontemporal_store via a native clang vector type
// (the HIP float4 class is rejected by the builtin).

#define B 32
#define C 64
#define H 64
#define W 64
#define HO 62
#define WO 62
#define L (HO * WO)   // 3844
#define L4 (L / 4)    // 961
#define KK 9          // KH*KW

typedef float f32x4 __attribute__((ext_vector_type(4)));

__device__ __forceinline__ int sw(int p) { return p + (p >> 5); }

__global__ __launch_bounds__(256) void unfold_kernel(
    const float* __restrict__ x, float* __restrict__ out) {
    __shared__ float tile[H * W + (H * W) / 32];  // 4096 + 128 floats = 16.9 KB

    const int c   = blockIdx.x;   // 0..63
    const int b   = blockIdx.y;   // 0..31
    const int tid = threadIdx.x;  // 0..255

    // ---- Stage channel (b,c): 4096 floats = 1024 float4, coalesced. ----
    const f32x4* __restrict__ src =
        (const f32x4*)(x + (((size_t)(b * C + c)) << 12));
#pragma unroll
    for (int r = 0; r < 4; ++r) {
        const int p4 = tid + r * 256;  // 0..1023
        f32x4 v = src[p4];
        const int p = p4 * 4;
        tile[sw(p)]     = v.x;   // stride-4 writes: conflict-free under swizzle
        tile[sw(p + 1)] = v.y;
        tile[sw(p + 2)] = v.z;
        tile[sw(p + 3)] = v.w;
    }
    __syncthreads();

    // ---- Emit: position-outer, k-inner (decode amortized over 9 planes). ----
    f32x4* __restrict__ dst =
        (f32x4*)out + (size_t)(b * C + c) * KK * L4;

#pragma unroll
    for (int r = 0; r < 4; ++r) {
        const int t = tid + r * 256;   // float4 index within a k-plane
        if (t < L4) {
            const int l0 = t * 4;
            int ho = l0 / WO;          // magic-mul division (once per position)
            int wo = l0 - ho * WO;
            int addr = ho * W + wo;    // unswizzled, base-free input address
            int a0, a1, a2, a3;
            a0 = addr; ++addr; ++wo; if (wo == WO) { wo = 0; addr += (W - WO); }
            a1 = addr; ++addr; ++wo; if (wo == WO) { wo = 0; addr += (W - WO); }
            a2 = addr; ++addr; ++wo; if (wo == WO) { wo = 0; addr += (W - WO); }
            a3 = addr;
#pragma unroll
            for (int k = 0; k < KK; ++k) {
                const int i    = k / 3;          // constants after unroll
                const int j    = k - i * 3;
                const int base = i * W + j;      // 0,1,2,64,65,66,128,129,130
                f32x4 v;
                v.x = tile[sw(a0 + base)];
                v.y = tile[sw(a1 + base)];
                v.z = tile[sw(a2 + base)];
                v.w = tile[sw(a3 + base)];
                // write-once 283 MB stream: bypass L2 retention
                __builtin_nontemporal_store(v, &dst[k * L4 + t]);
            }
        }
    }
}

extern "C" void kernel_launch(void* const* d_in, const int* in_sizes, int n_in,
                              void* d_out, int out_size, void* d_ws, size_t ws_size,
                              hipStream_t stream) {
    const float* x = (const float*)d_in[0];
    float* out = (float*)d_out;

    dim3 block(256, 1, 1);
    dim3 grid(C, B, 1);  // one block per (b,c) channel: 2048 blocks
    unfold_kernel<<<grid, block, 0, stream>>>(x, out);
}